// Round 10
// baseline (464.532 us; speedup 1.0000x reference)
//
#include <hip/hip_runtime.h>
#include <hip/hip_bf16.h>
#include <cmath>

typedef unsigned short ushortT;
typedef unsigned int u32;
typedef __attribute__((ext_vector_type(8))) short short8;
typedef __attribute__((ext_vector_type(4))) float floatx4;

#define IMG 14
#define NTOK 196          // 14*14
#define BATCH 64
#define M_TOT 12544       // 64*196
#define M_HALF 6272       // 49*128
#define INCH 384
#define OUTCH 768
#define HIDDEN 1536
#define HEADS 8
#define HDIM 32
#define SCALE 0.17677669529663687f

__device__ __forceinline__ float b2f(ushortT u) {
    union { u32 i; float f; } v; v.i = ((u32)u) << 16; return v.f;
}
__device__ __forceinline__ ushortT f2b(float f) {
    union { float f; u32 i; } v; v.f = f;
    u32 r = v.i + 0x7FFFu + ((v.i >> 16) & 1u);
    return (ushortT)(r >> 16);
}

__device__ __forceinline__ void async_ld16(const void* g, void* l) {
    __builtin_amdgcn_global_load_lds(
        (const __attribute__((address_space(1))) u32*)g,
        (__attribute__((address_space(3))) u32*)l, 16, 0, 0);
}

// ---------------------------------------------------------------- prep + pool + bias-expand
__global__ __launch_bounds__(256) void prep_pool(
    const float* __restrict__ Wqkv, const float* __restrict__ Wout,
    const float* __restrict__ Wfc1, const float* __restrict__ Wfc2,
    const float* __restrict__ Wproj, const float* __restrict__ x,
    const float* __restrict__ bias_tb,
    ushortT* __restrict__ oQkv, ushortT* __restrict__ oOut,
    ushortT* __restrict__ oFc1, ushortT* __restrict__ oFc2,
    ushortT* __restrict__ oProj, ushortT* __restrict__ pooled,
    float* __restrict__ bias_exp) {
    __shared__ __align__(16) char lds_raw[26880];
    int blk = blockIdx.x;
    int tid = threadIdx.x;
    if (blk >= 4608) {
        // ---------------- bias expansion: [8][208][208] fp32 ----------------
        int idx4 = (blk - 4608) * 256 + tid;          // 0..86527 (exact)
        int h = idx4 / 10816;                          // 208*208/4
        int rem = idx4 - h * 10816;
        int i = rem / 52;
        int j0 = (rem - i * 52) * 4;
        float v[4];
        #pragma unroll
        for (int u = 0; u < 4; ++u) {
            int j = j0 + u;
            float val = 0.f;
            if (i < 196 && j < 196) {
                int iy = i / 14, ix = i - iy * 14;
                int jy = j / 14, jx = j - jy * 14;
                val = bias_tb[((iy - jy + 13) * 27 + (ix - jx + 13)) * 8 + h];
            }
            v[u] = val;
        }
        *(float4*)(bias_exp + (size_t)idx4 * 4) = *(const float4*)v;
        return;
    }
    if (blk >= 3072) {
        // ---------------- maxpool (separable: horizontal 3-max, then vertical) ----
        int pblk = blk - 3072;
        int cg = pblk % 24, b = pblk / 24;
        float* hm = (float*)lds_raw;                  // [16][28][15]
        const float* xsrc = x + ((size_t)b * INCH + cg * 16) * 784;
        for (int t = tid; t < 448; t += 256) {
            int c = t / 28, hrow = t - c * 28;
            const float* rp = xsrc + c * 784 + hrow * 28;
            float r[28];
            #pragma unroll
            for (int u = 0; u < 7; ++u)
                *(float4*)(r + u * 4) = *(const float4*)(rp + u * 4);
            float* hr = hm + (size_t)t * 15;
            #pragma unroll
            for (int j = 0; j < 14; ++j) {
                float a = j ? r[2 * j - 1] : r[0];
                hr[j] = fmaxf(fmaxf(a, r[2 * j]), r[2 * j + 1]);
            }
        }
        __syncthreads();
        for (int chunk = tid; chunk < NTOK * 2; chunk += 256) {
            int n = chunk >> 1, q = chunk & 1;
            int hh = n / IMG, ww = n - hh * IMG;
            int ya = hh ? 2 * hh - 1 : 0;
            int y1 = 2 * hh, y2 = 2 * hh + 1;
            ushortT o[8];
            #pragma unroll
            for (int cc = 0; cc < 8; ++cc) {
                const float* base = hm + (size_t)(q * 8 + cc) * 28 * 15 + ww;
                float mv = fmaxf(fmaxf(base[ya * 15], base[y1 * 15]), base[y2 * 15]);
                o[cc] = f2b(mv);
            }
            *(uint4*)(pooled + ((size_t)b * NTOK + n) * INCH + cg * 16 + q * 8) =
                *(const uint4*)o;
        }
        return;
    }
    if (blk >= 2784) {   // convert segment (288 blocks x 1024 elems)
        int i = ((blk - 2784) * 256 + tid) * 4;
        float4 v = *(const float4*)(Wproj + i);
        ushortT o[4] = { f2b(v.x), f2b(v.y), f2b(v.z), f2b(v.w) };
        *(uint2*)(oProj + i) = *(const uint2*)o;
        return;
    }
    const float* in; ushortT* out; int R, C, tile;
    if (blk < 288)       { in = Wqkv; out = oQkv; R = 384;  C = 768;  tile = blk; }
    else if (blk < 480)  { in = Wout; out = oOut; R = 256;  C = 768;  tile = blk - 288; }
    else if (blk < 1632) { in = Wfc1; out = oFc1; R = 768;  C = 1536; tile = blk - 480; }
    else                 { in = Wfc2; out = oFc2; R = 1536; C = 768;  tile = blk - 1632; }
    int tilesX = C >> 5;
    int bx = (tile % tilesX) * 32, by = (tile / tilesX) * 32;
    ushortT (*t)[33] = (ushortT (*)[33])lds_raw;
    int tx = tid & 31, ty = tid >> 5;
    #pragma unroll
    for (int i = 0; i < 4; ++i) {
        int r = by + ty * 4 + i;
        t[ty * 4 + i][tx] = f2b(in[(size_t)r * C + bx + tx]);
    }
    __syncthreads();
    #pragma unroll
    for (int i = 0; i < 4; ++i) {
        int r = bx + ty * 4 + i;
        out[(size_t)r * R + by + tx] = t[tx][ty * 4 + i];
    }
}

// ---------------------------------------------------------------- layernorm (wave-per-row)
template <int VE>
__global__ __launch_bounds__(256) void ln_kernel(const ushortT* __restrict__ in,
                                                 const float* __restrict__ gw,
                                                 const float* __restrict__ bw,
                                                 ushortT* __restrict__ out) {
    constexpr int C = 192 * VE;
    int wave = threadIdx.x >> 6, lane = threadIdx.x & 63;
    int m = blockIdx.x * 4 + wave;
    const ushortT* row = in + (size_t)m * C;
    float v[3][VE];
    float s = 0.f, q = 0.f;
    #pragma unroll
    for (int seg = 0; seg < 3; ++seg) {
        int idx = seg * 64 * VE + lane * VE;
        ushortT tmp[VE];
        if constexpr (VE == 2) *(u32*)tmp = *(const u32*)(row + idx);
        else                   *(uint2*)tmp = *(const uint2*)(row + idx);
        #pragma unroll
        for (int k = 0; k < VE; ++k) {
            float f = b2f(tmp[k]);
            v[seg][k] = f;
            s += f;
            q += f * f;
        }
    }
    #pragma unroll
    for (int off = 32; off > 0; off >>= 1) {
        s += __shfl_xor(s, off, 64);
        q += __shfl_xor(q, off, 64);
    }
    float mu = s / (float)C;
    float var = q / (float)C - mu * mu;
    float rs = rsqrtf(var + 1e-5f);
    #pragma unroll
    for (int seg = 0; seg < 3; ++seg) {
        int idx = seg * 64 * VE + lane * VE;
        float g[VE], bb[VE];
        if constexpr (VE == 2) {
            *(float2*)g = *(const float2*)(gw + idx);
            *(float2*)bb = *(const float2*)(bw + idx);
        } else {
            *(float4*)g = *(const float4*)(gw + idx);
            *(float4*)bb = *(const float4*)(bw + idx);
        }
        ushortT o[VE];
        #pragma unroll
        for (int k = 0; k < VE; ++k)
            o[k] = f2b((v[seg][k] - mu) * rs * g[k] + bb[k]);
        if constexpr (VE == 2) *(u32*)(out + (size_t)m * C + idx) = *(const u32*)o;
        else                   *(uint2*)(out + (size_t)m * C + idx) = *(const uint2*)o;
    }
}

// ---------------------------------------------------------------- MFMA attention
// Q/K fragments loaded directly from global (L2-resident); LDS = Vts + Ps = 44.5 KB.
__global__ __launch_bounds__(256) void attn_kernel(const ushortT* __restrict__ qkv,
                                                   const float* __restrict__ bias_exp,
                                                   ushortT* __restrict__ attn_out) {
    int bh = blockIdx.x;
    int b = bh >> 3, h = bh & 7;
    __shared__ ushortT Vts[32 * 232];       // V^T, row stride 232 (16B aligned)
    __shared__ ushortT Ps[4][16 * 232];     // per-wave P strip
    const int tid = threadIdx.x, wave = tid >> 6, lane = tid & 63;

    const ushortT* qg = qkv + (size_t)bh * 6272;
    const ushortT* kg = qkv + (size_t)(512 + bh) * 6272;
    const uint4* v4 = (const uint4*)(qkv + (size_t)(1024 + bh) * 6272);
    // V transpose into Vts
    for (int t = tid; t < 784; t += 256) {
        int j = t >> 2, d0 = (t & 3) * 8;
        uint4 v = v4[t];
        const ushortT* vs = (const ushortT*)&v;
        #pragma unroll
        for (int u = 0; u < 8; ++u)
            Vts[(d0 + u) * 232 + j] = vs[u];
    }
    for (int t = tid; t < 1152; t += 256) {           // zero Vts cols 196..231
        int d = t / 36, j = 196 + t - d * 36;
        Vts[d * 232 + j] = 0;
    }
    for (int t = tid; t < 1536; t += 256) {           // zero Ps cols 208..231
        int w = t / 384, rem = t - w * 384;
        int row = rem / 24, j = 208 + rem - (rem / 24) * 24;
        Ps[w][row * 232 + j] = 0;
    }
    __syncthreads();

    const int fr = (lane & 15), fk = (lane >> 4) * 8;
    short8 kf[13];
    #pragma unroll
    for (int nt = 0; nt < 13; ++nt)
        kf[nt] = *(const short8*)(kg + (nt * 16 + fr) * 32 + fk);

    const int i0r = (lane >> 4) * 4;   // C-layout row base
    const int colL = lane & 15;        // C-layout col
    ushortT* Pw = &Ps[wave][0];

    for (int mt = wave; mt < 13; mt += 4) {
        short8 af = *(const short8*)(qg + (mt * 16 + fr) * 32 + fk);
        floatx4 sc[13];
        #pragma unroll
        for (int nt = 0; nt < 13; ++nt)
            sc[nt] = __builtin_amdgcn_mfma_f32_16x16x32_bf16(
                af, kf[nt], (floatx4){0.f, 0.f, 0.f, 0.f}, 0, 0, 0);

        float rsum[4] = {0.f, 0.f, 0.f, 0.f};
        const float* bb = bias_exp + ((size_t)h * 208 + mt * 16 + i0r) * 208 + colL;
        #pragma unroll
        for (int nt = 0; nt < 13; ++nt) {
            #pragma unroll
            for (int r = 0; r < 4; ++r) {
                float bias = bb[r * 208 + nt * 16];
                float p = __expf(sc[nt][r] * SCALE + bias);
                if (nt == 12 && colL >= 4) p = 0.f;   // mask j >= 196 (also kills garbage)
                rsum[r] += p;
                Pw[(i0r + r) * 232 + nt * 16 + colL] = f2b(p);
            }
        }
        #pragma unroll
        for (int off = 1; off < 16; off <<= 1) {
            #pragma unroll
            for (int r = 0; r < 4; ++r) rsum[r] += __shfl_xor(rsum[r], off, 64);
        }

        floatx4 o[2];
        o[0] = (floatx4){0.f, 0.f, 0.f, 0.f};
        o[1] = (floatx4){0.f, 0.f, 0.f, 0.f};
        #pragma unroll
        for (int kt = 0; kt < 7; ++kt) {
            short8 pf = *(const short8*)(Pw + fr * 232 + kt * 32 + fk);
            #pragma unroll
            for (int n2 = 0; n2 < 2; ++n2) {
                short8 vf = *(const short8*)(Vts + (n2 * 16 + fr) * 232 + kt * 32 + fk);
                o[n2] = __builtin_amdgcn_mfma_f32_16x16x32_bf16(pf, vf, o[n2], 0, 0, 0);
            }
        }
        float invl[4];
        #pragma unroll
        for (int r = 0; r < 4; ++r) invl[r] = 1.f / rsum[r];
        #pragma unroll
        for (int n2 = 0; n2 < 2; ++n2) {
            #pragma unroll
            for (int r = 0; r < 4; ++r) {
                int i = mt * 16 + i0r + r;
                if (i < 196)
                    attn_out[((size_t)(b * 196 + i)) * 256 + h * 32 + n2 * 16 + colL] =
                        f2b(o[n2][r] * invl[r]);
            }
        }
    }
}

// ---------------------------------------------------------------- BMx128 GEMM core (4-wave)
template <int BM>
__device__ __forceinline__ void gemm_core(
    const ushortT* __restrict__ A, const ushortT* __restrict__ B,
    int nsteps, int lda, int ldb, int tm, int tn,
    ushortT* As, ushortT* Bs, floatx4 (&acc)[BM / 32][4],
    int tid, int wave, int lane) {
    constexpr int MT = BM / 32;
    constexpr int ATILE = BM * 32;
    const int fr = lane & 15, fk = (lane >> 4) * 8;
    const int wr = (wave >> 1) * (BM / 2), wc = (wave & 1) * 64;
    auto stage = [&](int buf, int k0) {
        const ushortT* Ag = A + (size_t)(tm * BM) * lda + k0;
        const ushortT* Bg = B + (size_t)(tn * 128) * ldb + k0;
        ushortT* Al = As + buf * ATILE;
        ushortT* Bl = Bs + buf * 4096;
        #pragma unroll
        for (int i = 0; i < BM / 64; ++i) {
            int c = tid + i * 256;
            async_ld16(Ag + (size_t)(c >> 2) * lda + (c & 3) * 8, Al + c * 8);
        }
        #pragma unroll
        for (int i = 0; i < 2; ++i) {
            int c = tid + i * 256;
            async_ld16(Bg + (size_t)(c >> 2) * ldb + (c & 3) * 8, Bl + c * 8);
        }
    };
    stage(0, 0);
    for (int t = 0; t < nsteps; ++t) {
        __syncthreads();                       // drains vmcnt: buf[t&1] complete
        if (t + 1 < nsteps) stage((t + 1) & 1, (t + 1) * 32);
        const ushortT* Ab = As + (t & 1) * ATILE;
        const ushortT* Bb = Bs + (t & 1) * 4096;
        short8 af[MT], bf[4];
        #pragma unroll
        for (int mt = 0; mt < MT; ++mt)
            af[mt] = *(const short8*)(Ab + (wr + mt * 16 + fr) * 32 + fk);
        #pragma unroll
        for (int nt = 0; nt < 4; ++nt)
            bf[nt] = *(const short8*)(Bb + (wc + nt * 16 + fr) * 32 + fk);
        #pragma unroll
        for (int mt = 0; mt < MT; ++mt)
            #pragma unroll
            for (int nt = 0; nt < 4; ++nt)
                acc[mt][nt] = __builtin_amdgcn_mfma_f32_16x16x32_bf16(
                    af[mt], bf[nt], acc[mt][nt], 0, 0, 0);
    }
}

// ---------------------------------------------------------------- merged QKV + proj GEMM
__global__ __launch_bounds__(256) void gemm_qkvproj(
    const ushortT* __restrict__ tln1, const ushortT* __restrict__ wTqkv,
    const ushortT* __restrict__ pooled, const ushortT* __restrict__ wProjB,
    const float* __restrict__ b_out, ushortT* __restrict__ qkvb,
    float* __restrict__ outT) {
    __shared__ ushortT As[2 * 4096];
    __shared__ ushortT Bs[2 * 4096];
    const int tid = threadIdx.x, wave = tid >> 6, lane = tid & 63;
    const int tm = blockIdx.x;
    const int y = blockIdx.y;
    const bool isP = y >= 6;
    const int tn = isP ? y - 6 : y;
    const ushortT* A = isP ? pooled : tln1;
    const ushortT* B = isP ? wProjB : wTqkv;

    floatx4 acc[4][4];
    #pragma unroll
    for (int a = 0; a < 4; ++a)
        #pragma unroll
        for (int c = 0; c < 4; ++c)
            acc[a][c] = (floatx4){0.f, 0.f, 0.f, 0.f};

    gemm_core<128>(A, B, 12, 384, 384, tm, tn, As, Bs, acc, tid, wave, lane);

    const int wr = (wave >> 1) * 64, wc = (wave & 1) * 64;
    const int nb = tn * 128 + wc + (lane & 15);
    const int mbl = wr + ((lane >> 4) << 2);
    if (!isP) {
        #pragma unroll
        for (int nt = 0; nt < 4; ++nt) {
            int n = nb + nt * 16;
            int reg = n >> 8, head = (n >> 5) & 7, d = n & 31;
            #pragma unroll
            for (int mt = 0; mt < 4; ++mt) {
                #pragma unroll
                for (int r = 0; r < 4; ++r) {
                    int m = tm * 128 + mbl + mt * 16 + r;
                    int bb = m / 196, tok = m - bb * 196;
                    qkvb[((size_t)((reg * 512 + bb * 8 + head) * 196 + tok)) * 32 + d] =
                        f2b(acc[mt][nt][r]);
                }
            }
        }
    } else {
        #pragma unroll
        for (int nt = 0; nt < 4; ++nt) {
            int n = nb + nt * 16;
            float bv = b_out[n];
            #pragma unroll
            for (int mt = 0; mt < 4; ++mt) {
                int m0 = tm * 128 + mbl + mt * 16;       // multiple of 4
                int bb = m0 / 196, tok = m0 - bb * 196;  // tok mult of 4, no bb split
                float vv[4];
                #pragma unroll
                for (int r = 0; r < 4; ++r) vv[r] = acc[mt][nt][r] + bv;
                *(float4*)(outT + ((size_t)(bb * 768 + n)) * 196 + tok) =
                    *(const float4*)vv;
            }
        }
    }
}

// ---------------------------------------------------------------- wout GEMM (4-wave)
// EPI 1: wout — v + outT(float4 RMW) -> outT fp32, + htok bf16 copy for LN2
__global__ __launch_bounds__(256) void gemm_wout(
    const ushortT* __restrict__ A, const ushortT* __restrict__ B, int K,
    ushortT* __restrict__ outb, float* __restrict__ outT) {
    __shared__ ushortT As[2 * 4096];
    __shared__ ushortT Bs[2 * 4096];
    const int tid = threadIdx.x, wave = tid >> 6, lane = tid & 63;
    const int tm = blockIdx.x, tn = blockIdx.y;

    floatx4 acc[4][4];
    #pragma unroll
    for (int a = 0; a < 4; ++a)
        #pragma unroll
        for (int c = 0; c < 4; ++c)
            acc[a][c] = (floatx4){0.f, 0.f, 0.f, 0.f};

    gemm_core<128>(A, B, K >> 5, K, K, tm, tn, As, Bs, acc, tid, wave, lane);

    const int wr = (wave >> 1) * 64, wc = (wave & 1) * 64;
    const int nb = tn * 128 + wc + (lane & 15);
    const int mbl = wr + ((lane >> 4) << 2);
    #pragma unroll
    for (int nt = 0; nt < 4; ++nt) {
        int n = nb + nt * 16;
        #pragma unroll
        for (int mt = 0; mt < 4; ++mt) {
            int m0 = tm * 128 + mbl + mt * 16;
            int bb = m0 / 196, tok = m0 - bb * 196;
            float* p = outT + ((size_t)(bb * 768 + n)) * 196 + tok;
            float hv[4];
            *(float4*)hv = *(const float4*)p;
            float vv[4];
            #pragma unroll
            for (int r = 0; r < 4; ++r) vv[r] = acc[mt][nt][r] + hv[r];
            *(float4*)p = *(const float4*)vv;
            #pragma unroll
            for (int r = 0; r < 4; ++r)
                outb[(size_t)(m0 + r) * 768 + n] = f2b(vv[r]);
        }
    }
}

// ---------------------------------------------------------------- 8-wave phase-pipelined GEMM
// BM=BN=128, BK=64, 512 threads (8 waves as 4M x 2N, per-wave 32x64 out, acc[2][4]).
// 3 LDS buffers (96 KB), depth-2 prefetch, counted vmcnt(4) ONLY at phase 0 of each
// K-tile (never 0 mid-loop); 2 phases per K-tile, each: barrier -> stage-issue (A or
// B) -> ds_read frags -> setprio(1) -> 8 MFMA -> setprio(0). Loads stay in flight
// across raw barriers (T3/T4); setprio has 8-wave role diversity to arbitrate (T5).
// BK=64 needs LDS swizzle (128B rows = 16-way alias, r7): rule #21 — linear
// global_load_lds dest + pre-swizzled GLOBAL source + same XOR on ds_read.
//   LDS elem (row, c) holds global elem col = c ^ ((row&7)<<3).
//   Stage: lane of wave-instr writes row = w*8+i*64+(lane>>3), LDS col (lane&7)*8,
//          so its global col-chunk = ((lane&7)^(lane>>3))*8 — per-row coalesced.
//   Read:  af/bf at elem col c_e read LDS col c_e ^ ((r&7)<<3) -> 8-way spread (floor).
// Race audit: stage target (t+2)%3 == (t-1)%3, read in iter t-1, retired before each
// wave's iter-t p0 barrier; stage issue is after that barrier. Tile-t visibility:
// all waves vmcnt(4) THEN barrier at p0.
template <int EPI>
__global__ __launch_bounds__(512) void gemm8p(
    const ushortT* __restrict__ A, const ushortT* __restrict__ B, int K,
    const float* __restrict__ bias, ushortT* __restrict__ outb,
    float* __restrict__ outT, int m_off) {
    __shared__ ushortT As[3][128 * 64];
    __shared__ ushortT Bs[3][128 * 64];
    const int tid = threadIdx.x, wave = tid >> 6, lane = tid & 63;
    const int tm = blockIdx.x, tn = blockIdx.y;
    const int fr = lane & 15, fk = (lane >> 4) * 8;
    const int wr = (wave >> 1) * 32, wc = (wave & 1) * 64;

    const int srow = wave * 8 + (lane >> 3);             // staging row (i adds 64)
    const int scol = ((lane & 7) ^ (lane >> 3)) << 3;    // pre-swizzled global col
    const int ldst = wave * 512 + lane * 8;              // linear LDS dest (ushorts)
    const ushortT* gA = A + (size_t)(tm * 128 + srow) * K + scol;
    const ushortT* gB = B + (size_t)(tn * 128 + srow) * K + scol;

    auto stageA = [&](int buf, int k0) {
        async_ld16(gA + k0, &As[buf][ldst]);
        async_ld16(gA + (size_t)64 * K + k0, &As[buf][ldst + 4096]);
    };
    auto stageB = [&](int buf, int k0) {
        async_ld16(gB + k0, &Bs[buf][ldst]);
        async_ld16(gB + (size_t)64 * K + k0, &Bs[buf][ldst + 4096]);
    };

    floatx4 acc[2][4];
    #pragma unroll
    for (int a = 0; a < 2; ++a)
        #pragma unroll
        for (int c = 0; c < 4; ++c)
            acc[a][c] = (floatx4){0.f, 0.f, 0.f, 0.f};

    const int nsteps = K >> 6;                 // K-tiles of 64
    stageA(0, 0); stageB(0, 0);
    stageA(1, 64); stageB(1, 64);
    for (int t = 0; t < nsteps; ++t) {
        const ushortT* Ab = As[t % 3];
        const ushortT* Bb = Bs[t % 3];
        #pragma unroll
        for (int p = 0; p < 2; ++p) {
            if (p == 0) {
                if (t + 1 < nsteps) asm volatile("s_waitcnt vmcnt(4)" ::: "memory");
                else                asm volatile("s_waitcnt vmcnt(0)" ::: "memory");
            }
            __builtin_amdgcn_s_barrier();
            __builtin_amdgcn_sched_barrier(0);
            if (t + 2 < nsteps) {
                if (p == 0) stageA((t + 2) % 3, (t + 2) * 64);
                else        stageB((t + 2) % 3, (t + 2) * 64);
            }
            short8 af[2], bf[4];
            #pragma unroll
            for (int mt = 0; mt < 2; ++mt) {
                int r = wr + mt * 16 + fr;
                af[mt] = *(const short8*)(Ab + r * 64 + ((p * 32 + fk) ^ ((r & 7) << 3)));
            }
            #pragma unroll
            for (int nt = 0; nt < 4; ++nt) {
                int r = wc + nt * 16 + fr;
                bf[nt] = *(const short8*)(Bb + r * 64 + ((p * 32 + fk) ^ ((r & 7) << 3)));
            }
            __builtin_amdgcn_s_setprio(1);
            #pragma unroll
            for (int mt = 0; mt < 2; ++mt)
                #pragma unroll
                for (int nt = 0; nt < 4; ++nt)
                    acc[mt][nt] = __builtin_amdgcn_mfma_f32_16x16x32_bf16(
                        af[mt], bf[nt], acc[mt][nt], 0, 0, 0);
            __builtin_amdgcn_s_setprio(0);
        }
    }

    const int nb = tn * 128 + wc + fr;
    const int mbl = wr + ((lane >> 4) << 2);
    #pragma unroll
    for (int nt = 0; nt < 4; ++nt) {
        int n = nb + nt * 16;
        float bv = bias[n];
        #pragma unroll
        for (int mt = 0; mt < 2; ++mt) {
            int m0 = tm * 128 + mbl + mt * 16;
            if constexpr (EPI == 2) {
                #pragma unroll
                for (int r = 0; r < 4; ++r) {
                    float v = acc[mt][nt][r] + bv;
                    float gl = 0.5f * v * (1.f + erff(v * 0.70710678118654752f));
                    outb[(size_t)(m0 + r) * 1536 + n] = f2b(gl);
                }
            } else {
                int mg = m0 + m_off;
                int bb = mg / 196, tok = mg - bb * 196;
                float* p = outT + ((size_t)(bb * 768 + n)) * 196 + tok;
                float hv[4];
                *(float4*)hv = *(const float4*)p;
                float vv[4];
                #pragma unroll
                for (int r = 0; r < 4; ++r) vv[r] = acc[mt][nt][r] + bv + hv[r];
                *(float4*)p = *(const float4*)vv;
            }
        }
    }
}

// ---------------------------------------------------------------- launch
extern "C" void kernel_launch(void* const* d_in, const int* in_sizes, int n_in,
                              void* d_out, int out_size, void* d_ws, size_t ws_size,
                              hipStream_t stream) {
    const float* x       = (const float*)d_in[0];
    const float* W_qkv   = (const float*)d_in[1];
    const float* bias_tb = (const float*)d_in[2];
    const float* W_out   = (const float*)d_in[3];
    const float* b_out   = (const float*)d_in[4];
    const float* ln1_g   = (const float*)d_in[5];
    const float* ln1_b   = (const float*)d_in[6];
    const float* ln2_g   = (const float*)d_in[7];
    const float* ln2_b   = (const float*)d_in[8];
    const float* W_fc1   = (const float*)d_in[9];
    const float* b_fc1   = (const float*)d_in[10];
    const float* W_fc2   = (const float*)d_in[11];
    const float* b_fc2   = (const float*)d_in[12];
    const float* W_proj  = (const float*)d_in[13];
    float* out = (float*)d_out;

    char* ws = (char*)d_ws;
    ushortT* pooled = (ushortT*)(ws);                 // [12544][384]
    ushortT* tln1   = (ushortT*)(ws + 9633792);       // [12544][384]
    ushortT* attno  = tln1;                           // reuse
    ushortT* qkvb   = (ushortT*)(ws + 19267584);      // [3][64][8][196][32]
    ushortT* tln2   = qkvb;                           // reuse (after attn)
    ushortT* mid    = (ushortT*)(ws);                 // [6272][1536] reuse (half path)
    ushortT* htok   = (ushortT*)(ws + 38535168);      // [12544][768]
    // bias_exp aliases htok region: written by prep, read by attn, then htok is
    // written (by wout gemm) strictly AFTER attn -> stream-safe.
    float*   bias_exp = (float*)(ws + 38535168);      // 1,384,448 B
    ushortT* wTqkv  = (ushortT*)(ws + 57802752);      // [768][384]
    ushortT* wTout  = wTqkv + 768 * 384;              // [768][256]
    ushortT* wTfc1  = wTout + 768 * 256;              // [1536][768]
    ushortT* wTfc2  = wTfc1 + 1536 * 768;             // [768][1536]
    ushortT* wProjB = wTfc2 + 768 * 1536;             // [768][384]
    const size_t weights_end = 57802752 +
        (size_t)(768 * 384 + 768 * 256 + 1536 * 768 + 768 * 1536 + 768 * 384) * 2;
    const bool ffn_full = ws_size >= weights_end + (size_t)M_TOT * HIDDEN * 2;
    ushortT* midf = (ushortT*)(ws + weights_end);

    // merged weight prep + pool + bias expansion
    prep_pool<<<4946, 256, 0, stream>>>(W_qkv, W_out, W_fc1, W_fc2, W_proj, x, bias_tb,
                                        wTqkv, wTout, wTfc1, wTfc2, wProjB, pooled,
                                        bias_exp);

    // LN1
    ln_kernel<2><<<M_TOT / 4, 256, 0, stream>>>(pooled, ln1_g, ln1_b, tln1);

    // QKV gemm + proj gemm merged (proj -> out fp32 transposed, + b_out)
    gemm_qkvproj<<<dim3(98, 12), 256, 0, stream>>>(tln1, wTqkv, pooled, wProjB,
                                                   b_out, qkvb, out);
    // MFMA attention
    attn_kernel<<<512, 256, 0, stream>>>(qkvb, bias_exp, attno);

    // h = attn_out @ W_out^T + (proj already in out); writes out fp32 + htok bf16
    gemm_wout<<<dim3(98, 6), 256, 0, stream>>>(attno, wTout, 256, htok, out);
    // LN2
    ln_kernel<4><<<M_TOT / 4, 256, 0, stream>>>(htok, ln2_g, ln2_b, tln2);

    if (ffn_full) {
        gemm8p<2><<<dim3(98, 12), 512, 0, stream>>>(tln2, wTfc1, 768,
                                                    b_fc1, midf, nullptr, 0);
        gemm8p<3><<<dim3(98, 6), 512, 0, stream>>>(midf, wTfc2, 1536,
                                                   b_fc2, nullptr, out, 0);
    } else {
        for (int half = 0; half < 2; ++half) {
            const ushortT* a2 = tln2 + (size_t)half * M_HALF * 768;
            gemm8p<2><<<dim3(49, 12), 512, 0, stream>>>(a2, wTfc1, 768,
                                                        b_fc1, mid, nullptr, 0);
            gemm8p<3><<<dim3(49, 6), 512, 0, stream>>>(mid, wTfc2, 1536,
                                                       b_fc2, nullptr, out,
                                                       half * M_HALF);
        }
    }
    (void)in_sizes; (void)n_in; (void)out_size; (void)ws_size;
}

// Round 11
// 373.660 us; speedup vs baseline: 1.2432x; 1.2432x over previous
//
#include <hip/hip_runtime.h>
#include <hip/hip_bf16.h>
#include <cmath>

typedef unsigned short ushortT;
typedef unsigned int u32;
typedef __attribute__((ext_vector_type(8))) short short8;
typedef __attribute__((ext_vector_type(4))) float floatx4;

#define IMG 14
#define NTOK 196          // 14*14
#define BATCH 64
#define M_TOT 12544       // 64*196
#define M_HALF 6272       // 49*128
#define INCH 384
#define OUTCH 768
#define HIDDEN 1536
#define HEADS 8
#define HDIM 32
#define SCALE 0.17677669529663687f

__device__ __forceinline__ float b2f(ushortT u) {
    union { u32 i; float f; } v; v.i = ((u32)u) << 16; return v.f;
}
__device__ __forceinline__ ushortT f2b(float f) {
    union { float f; u32 i; } v; v.f = f;
    u32 r = v.i + 0x7FFFu + ((v.i >> 16) & 1u);
    return (ushortT)(r >> 16);
}

__device__ __forceinline__ void async_ld16(const void* g, void* l) {
    __builtin_amdgcn_global_load_lds(
        (const __attribute__((address_space(1))) u32*)g,
        (__attribute__((address_space(3))) u32*)l, 16, 0, 0);
}

// Bijective XCD-chunked swizzle (m204): dispatch-linear id i round-robins XCDs;
// remap so each XCD owns a CONTIGUOUS tm-major range -> per-XCD L2 keeps an A-panel
// slice + full B weights resident (FETCH cut + 900cy HBM miss -> ~200cy L2 hit).
__device__ __forceinline__ void xcd_remap(int& tm, int& tn) {
    int nx = gridDim.x, ny = gridDim.y;
    int nwg = nx * ny;
    int i = blockIdx.y * nx + blockIdx.x;
    int q = nwg >> 3, r = nwg & 7;
    int xcd = i & 7, j = i >> 3;
    int wg = (xcd < r ? xcd * (q + 1) : r * (q + 1) + (xcd - r) * q) + j;
    tm = wg / ny;
    tn = wg - tm * ny;
}

// ---------------------------------------------------------------- prep + pool + bias-expand
__global__ __launch_bounds__(256) void prep_pool(
    const float* __restrict__ Wqkv, const float* __restrict__ Wout,
    const float* __restrict__ Wfc1, const float* __restrict__ Wfc2,
    const float* __restrict__ Wproj, const float* __restrict__ x,
    const float* __restrict__ bias_tb,
    ushortT* __restrict__ oQkv, ushortT* __restrict__ oOut,
    ushortT* __restrict__ oFc1, ushortT* __restrict__ oFc2,
    ushortT* __restrict__ oProj, ushortT* __restrict__ pooled,
    float* __restrict__ bias_exp) {
    __shared__ __align__(16) char lds_raw[26880];
    int blk = blockIdx.x;
    int tid = threadIdx.x;
    if (blk >= 4608) {
        // ---------------- bias expansion: [8][208][208] fp32 ----------------
        int idx4 = (blk - 4608) * 256 + tid;          // 0..86527 (exact)
        int h = idx4 / 10816;                          // 208*208/4
        int rem = idx4 - h * 10816;
        int i = rem / 52;
        int j0 = (rem - i * 52) * 4;
        float v[4];
        #pragma unroll
        for (int u = 0; u < 4; ++u) {
            int j = j0 + u;
            float val = 0.f;
            if (i < 196 && j < 196) {
                int iy = i / 14, ix = i - iy * 14;
                int jy = j / 14, jx = j - jy * 14;
                val = bias_tb[((iy - jy + 13) * 27 + (ix - jx + 13)) * 8 + h];
            }
            v[u] = val;
        }
        *(float4*)(bias_exp + (size_t)idx4 * 4) = *(const float4*)v;
        return;
    }
    if (blk >= 3072) {
        // ---------------- maxpool (separable: horizontal 3-max, then vertical) ----
        int pblk = blk - 3072;
        int cg = pblk % 24, b = pblk / 24;
        float* hm = (float*)lds_raw;                  // [16][28][15]
        const float* xsrc = x + ((size_t)b * INCH + cg * 16) * 784;
        for (int t = tid; t < 448; t += 256) {
            int c = t / 28, hrow = t - c * 28;
            const float* rp = xsrc + c * 784 + hrow * 28;
            float r[28];
            #pragma unroll
            for (int u = 0; u < 7; ++u)
                *(float4*)(r + u * 4) = *(const float4*)(rp + u * 4);
            float* hr = hm + (size_t)t * 15;
            #pragma unroll
            for (int j = 0; j < 14; ++j) {
                float a = j ? r[2 * j - 1] : r[0];
                hr[j] = fmaxf(fmaxf(a, r[2 * j]), r[2 * j + 1]);
            }
        }
        __syncthreads();
        for (int chunk = tid; chunk < NTOK * 2; chunk += 256) {
            int n = chunk >> 1, q = chunk & 1;
            int hh = n / IMG, ww = n - hh * IMG;
            int ya = hh ? 2 * hh - 1 : 0;
            int y1 = 2 * hh, y2 = 2 * hh + 1;
            ushortT o[8];
            #pragma unroll
            for (int cc = 0; cc < 8; ++cc) {
                const float* base = hm + (size_t)(q * 8 + cc) * 28 * 15 + ww;
                float mv = fmaxf(fmaxf(base[ya * 15], base[y1 * 15]), base[y2 * 15]);
                o[cc] = f2b(mv);
            }
            *(uint4*)(pooled + ((size_t)b * NTOK + n) * INCH + cg * 16 + q * 8) =
                *(const uint4*)o;
        }
        return;
    }
    if (blk >= 2784) {   // convert segment (288 blocks x 1024 elems)
        int i = ((blk - 2784) * 256 + tid) * 4;
        float4 v = *(const float4*)(Wproj + i);
        ushortT o[4] = { f2b(v.x), f2b(v.y), f2b(v.z), f2b(v.w) };
        *(uint2*)(oProj + i) = *(const uint2*)o;
        return;
    }
    const float* in; ushortT* out; int R, C, tile;
    if (blk < 288)       { in = Wqkv; out = oQkv; R = 384;  C = 768;  tile = blk; }
    else if (blk < 480)  { in = Wout; out = oOut; R = 256;  C = 768;  tile = blk - 288; }
    else if (blk < 1632) { in = Wfc1; out = oFc1; R = 768;  C = 1536; tile = blk - 480; }
    else                 { in = Wfc2; out = oFc2; R = 1536; C = 768;  tile = blk - 1632; }
    int tilesX = C >> 5;
    int bx = (tile % tilesX) * 32, by = (tile / tilesX) * 32;
    ushortT (*t)[33] = (ushortT (*)[33])lds_raw;
    int tx = tid & 31, ty = tid >> 5;
    #pragma unroll
    for (int i = 0; i < 4; ++i) {
        int r = by + ty * 4 + i;
        t[ty * 4 + i][tx] = f2b(in[(size_t)r * C + bx + tx]);
    }
    __syncthreads();
    #pragma unroll
    for (int i = 0; i < 4; ++i) {
        int r = bx + ty * 4 + i;
        out[(size_t)r * R + by + tx] = t[tx][ty * 4 + i];
    }
}

// ---------------------------------------------------------------- layernorm (wave-per-row)
template <int VE>
__global__ __launch_bounds__(256) void ln_kernel(const ushortT* __restrict__ in,
                                                 const float* __restrict__ gw,
                                                 const float* __restrict__ bw,
                                                 ushortT* __restrict__ out) {
    constexpr int C = 192 * VE;
    int wave = threadIdx.x >> 6, lane = threadIdx.x & 63;
    int m = blockIdx.x * 4 + wave;
    const ushortT* row = in + (size_t)m * C;
    float v[3][VE];
    float s = 0.f, q = 0.f;
    #pragma unroll
    for (int seg = 0; seg < 3; ++seg) {
        int idx = seg * 64 * VE + lane * VE;
        ushortT tmp[VE];
        if constexpr (VE == 2) *(u32*)tmp = *(const u32*)(row + idx);
        else                   *(uint2*)tmp = *(const uint2*)(row + idx);
        #pragma unroll
        for (int k = 0; k < VE; ++k) {
            float f = b2f(tmp[k]);
            v[seg][k] = f;
            s += f;
            q += f * f;
        }
    }
    #pragma unroll
    for (int off = 32; off > 0; off >>= 1) {
        s += __shfl_xor(s, off, 64);
        q += __shfl_xor(q, off, 64);
    }
    float mu = s / (float)C;
    float var = q / (float)C - mu * mu;
    float rs = rsqrtf(var + 1e-5f);
    #pragma unroll
    for (int seg = 0; seg < 3; ++seg) {
        int idx = seg * 64 * VE + lane * VE;
        float g[VE], bb[VE];
        if constexpr (VE == 2) {
            *(float2*)g = *(const float2*)(gw + idx);
            *(float2*)bb = *(const float2*)(bw + idx);
        } else {
            *(float4*)g = *(const float4*)(gw + idx);
            *(float4*)bb = *(const float4*)(bw + idx);
        }
        ushortT o[VE];
        #pragma unroll
        for (int k = 0; k < VE; ++k)
            o[k] = f2b((v[seg][k] - mu) * rs * g[k] + bb[k]);
        if constexpr (VE == 2) *(u32*)(out + (size_t)m * C + idx) = *(const u32*)o;
        else                   *(uint2*)(out + (size_t)m * C + idx) = *(const uint2*)o;
    }
}

// ---------------------------------------------------------------- MFMA attention
// Q/K fragments loaded directly from global (L2-resident); LDS = Vts + Ps = 44.5 KB.
__global__ __launch_bounds__(256) void attn_kernel(const ushortT* __restrict__ qkv,
                                                   const float* __restrict__ bias_exp,
                                                   ushortT* __restrict__ attn_out) {
    int bh = blockIdx.x;
    int b = bh >> 3, h = bh & 7;
    __shared__ ushortT Vts[32 * 232];       // V^T, row stride 232 (16B aligned)
    __shared__ ushortT Ps[4][16 * 232];     // per-wave P strip
    const int tid = threadIdx.x, wave = tid >> 6, lane = tid & 63;

    const ushortT* qg = qkv + (size_t)bh * 6272;
    const ushortT* kg = qkv + (size_t)(512 + bh) * 6272;
    const uint4* v4 = (const uint4*)(qkv + (size_t)(1024 + bh) * 6272);
    // V transpose into Vts
    for (int t = tid; t < 784; t += 256) {
        int j = t >> 2, d0 = (t & 3) * 8;
        uint4 v = v4[t];
        const ushortT* vs = (const ushortT*)&v;
        #pragma unroll
        for (int u = 0; u < 8; ++u)
            Vts[(d0 + u) * 232 + j] = vs[u];
    }
    for (int t = tid; t < 1152; t += 256) {           // zero Vts cols 196..231
        int d = t / 36, j = 196 + t - d * 36;
        Vts[d * 232 + j] = 0;
    }
    for (int t = tid; t < 1536; t += 256) {           // zero Ps cols 208..231
        int w = t / 384, rem = t - w * 384;
        int row = rem / 24, j = 208 + rem - (rem / 24) * 24;
        Ps[w][row * 232 + j] = 0;
    }
    __syncthreads();

    const int fr = (lane & 15), fk = (lane >> 4) * 8;
    short8 kf[13];
    #pragma unroll
    for (int nt = 0; nt < 13; ++nt)
        kf[nt] = *(const short8*)(kg + (nt * 16 + fr) * 32 + fk);

    const int i0r = (lane >> 4) * 4;   // C-layout row base
    const int colL = lane & 15;        // C-layout col
    ushortT* Pw = &Ps[wave][0];

    for (int mt = wave; mt < 13; mt += 4) {
        short8 af = *(const short8*)(qg + (mt * 16 + fr) * 32 + fk);
        floatx4 sc[13];
        #pragma unroll
        for (int nt = 0; nt < 13; ++nt)
            sc[nt] = __builtin_amdgcn_mfma_f32_16x16x32_bf16(
                af, kf[nt], (floatx4){0.f, 0.f, 0.f, 0.f}, 0, 0, 0);

        float rsum[4] = {0.f, 0.f, 0.f, 0.f};
        const float* bb = bias_exp + ((size_t)h * 208 + mt * 16 + i0r) * 208 + colL;
        #pragma unroll
        for (int nt = 0; nt < 13; ++nt) {
            #pragma unroll
            for (int r = 0; r < 4; ++r) {
                float bias = bb[r * 208 + nt * 16];
                float p = __expf(sc[nt][r] * SCALE + bias);
                if (nt == 12 && colL >= 4) p = 0.f;   // mask j >= 196 (also kills garbage)
                rsum[r] += p;
                Pw[(i0r + r) * 232 + nt * 16 + colL] = f2b(p);
            }
        }
        #pragma unroll
        for (int off = 1; off < 16; off <<= 1) {
            #pragma unroll
            for (int r = 0; r < 4; ++r) rsum[r] += __shfl_xor(rsum[r], off, 64);
        }

        floatx4 o[2];
        o[0] = (floatx4){0.f, 0.f, 0.f, 0.f};
        o[1] = (floatx4){0.f, 0.f, 0.f, 0.f};
        #pragma unroll
        for (int kt = 0; kt < 7; ++kt) {
            short8 pf = *(const short8*)(Pw + fr * 232 + kt * 32 + fk);
            #pragma unroll
            for (int n2 = 0; n2 < 2; ++n2) {
                short8 vf = *(const short8*)(Vts + (n2 * 16 + fr) * 232 + kt * 32 + fk);
                o[n2] = __builtin_amdgcn_mfma_f32_16x16x32_bf16(pf, vf, o[n2], 0, 0, 0);
            }
        }
        float invl[4];
        #pragma unroll
        for (int r = 0; r < 4; ++r) invl[r] = 1.f / rsum[r];
        #pragma unroll
        for (int n2 = 0; n2 < 2; ++n2) {
            #pragma unroll
            for (int r = 0; r < 4; ++r) {
                int i = mt * 16 + i0r + r;
                if (i < 196)
                    attn_out[((size_t)(b * 196 + i)) * 256 + h * 32 + n2 * 16 + colL] =
                        f2b(o[n2][r] * invl[r]);
            }
        }
    }
}

// ---------------------------------------------------------------- pipelined 128x128 core
// r5 structure (best measured): 3-buffer, depth-2 prefetch, counted vmcnt; each wave
// waits only its own 4 current-tile loads (vmcnt(4)) then barriers; tile t+1's loads
// stay in flight across the barrier; then issue tile t+2. sched_barrier(0) pins the
// post-barrier ds_reads below the raw barrier (rule #18).
__device__ __forceinline__ void gemm_core128(
    const ushortT* __restrict__ A, const ushortT* __restrict__ B, int K,
    int tm, int tn, ushortT* As, ushortT* Bs,
    floatx4 (&acc)[4][4], int tid, int wave, int lane) {
    const int fr = lane & 15, fk = (lane >> 4) * 8;
    const int wr = (wave >> 1) * 64, wc = (wave & 1) * 64;
    auto stage = [&](int buf, int k0) {
        const ushortT* Ag = A + (size_t)(tm * 128) * K + k0;
        const ushortT* Bg = B + (size_t)(tn * 128) * K + k0;
        ushortT* Al = As + buf * 4096;
        ushortT* Bl = Bs + buf * 4096;
        #pragma unroll
        for (int i = 0; i < 2; ++i) {
            int c = tid + i * 256;
            async_ld16(Ag + (size_t)(c >> 2) * K + (c & 3) * 8, Al + c * 8);
        }
        #pragma unroll
        for (int i = 0; i < 2; ++i) {
            int c = tid + i * 256;
            async_ld16(Bg + (size_t)(c >> 2) * K + (c & 3) * 8, Bl + c * 8);
        }
    };
    const int nsteps = K >> 5;
    stage(0, 0);
    if (nsteps > 1) stage(1, 32);
    for (int t = 0; t < nsteps; ++t) {
        if (t + 1 < nsteps) asm volatile("s_waitcnt vmcnt(4)" ::: "memory");
        else                asm volatile("s_waitcnt vmcnt(0)" ::: "memory");
        __builtin_amdgcn_s_barrier();          // all waves: buf[t%3] fully in LDS
        __builtin_amdgcn_sched_barrier(0);     // keep ds_reads below the barrier
        if (t + 2 < nsteps) stage((t + 2) % 3, (t + 2) * 32);
        const ushortT* Ab = As + (t % 3) * 4096;
        const ushortT* Bb = Bs + (t % 3) * 4096;
        short8 af[4], bf[4];
        #pragma unroll
        for (int mt = 0; mt < 4; ++mt)
            af[mt] = *(const short8*)(Ab + (wr + mt * 16 + fr) * 32 + fk);
        #pragma unroll
        for (int nt = 0; nt < 4; ++nt)
            bf[nt] = *(const short8*)(Bb + (wc + nt * 16 + fr) * 32 + fk);
        #pragma unroll
        for (int mt = 0; mt < 4; ++mt)
            #pragma unroll
            for (int nt = 0; nt < 4; ++nt)
                acc[mt][nt] = __builtin_amdgcn_mfma_f32_16x16x32_bf16(
                    af[mt], bf[nt], acc[mt][nt], 0, 0, 0);
    }
}

// ---------------------------------------------------------------- merged QKV + proj GEMM
// swizzled y in [0,6): qkv -> qkvb scatter; y in [6,12): proj + b_out -> outT fp32
__global__ __launch_bounds__(256) void gemm_qkvproj(
    const ushortT* __restrict__ tln1, const ushortT* __restrict__ wTqkv,
    const ushortT* __restrict__ pooled, const ushortT* __restrict__ wProjB,
    const float* __restrict__ b_out, ushortT* __restrict__ qkvb,
    float* __restrict__ outT) {
    __shared__ ushortT As[3 * 4096];
    __shared__ ushortT Bs[3 * 4096];
    const int tid = threadIdx.x, wave = tid >> 6, lane = tid & 63;
    int tm, y;
    xcd_remap(tm, y);
    const bool isP = y >= 6;
    const int tn = isP ? y - 6 : y;
    const ushortT* A = isP ? pooled : tln1;
    const ushortT* B = isP ? wProjB : wTqkv;

    floatx4 acc[4][4];
    #pragma unroll
    for (int a = 0; a < 4; ++a)
        #pragma unroll
        for (int c = 0; c < 4; ++c)
            acc[a][c] = (floatx4){0.f, 0.f, 0.f, 0.f};

    gemm_core128(A, B, 384, tm, tn, As, Bs, acc, tid, wave, lane);

    const int wr = (wave >> 1) * 64, wc = (wave & 1) * 64;
    const int nb = tn * 128 + wc + (lane & 15);
    const int mbl = wr + ((lane >> 4) << 2);
    if (!isP) {
        #pragma unroll
        for (int nt = 0; nt < 4; ++nt) {
            int n = nb + nt * 16;
            int reg = n >> 8, head = (n >> 5) & 7, d = n & 31;
            #pragma unroll
            for (int mt = 0; mt < 4; ++mt) {
                #pragma unroll
                for (int r = 0; r < 4; ++r) {
                    int m = tm * 128 + mbl + mt * 16 + r;
                    int bb = m / 196, tok = m - bb * 196;
                    qkvb[((size_t)((reg * 512 + bb * 8 + head) * 196 + tok)) * 32 + d] =
                        f2b(acc[mt][nt][r]);
                }
            }
        }
    } else {
        #pragma unroll
        for (int nt = 0; nt < 4; ++nt) {
            int n = nb + nt * 16;
            float bv = b_out[n];
            #pragma unroll
            for (int mt = 0; mt < 4; ++mt) {
                int m0 = tm * 128 + mbl + mt * 16;       // multiple of 4
                int bb = m0 / 196, tok = m0 - bb * 196;  // tok mult of 4, no bb split
                float vv[4];
                #pragma unroll
                for (int r = 0; r < 4; ++r) vv[r] = acc[mt][nt][r] + bv;
                *(float4*)(outT + ((size_t)(bb * 768 + n)) * 196 + tok) =
                    *(const float4*)vv;
            }
        }
    }
}

// ---------------------------------------------------------------- pipelined GEMM kernels
// EPI 1: wout   — v + outT(float4 RMW) -> outT fp32, + htok bf16 copy for LN2
// EPI 2: fc1    — gelu(v + bias)       -> outb bf16 [m][1536]
// EPI 3: fc2    — v + bias + outT(float4 RMW) -> outT fp32
template <int EPI>
__global__ __launch_bounds__(256) void gemm128p(
    const ushortT* __restrict__ A, const ushortT* __restrict__ B, int K,
    const float* __restrict__ bias, ushortT* __restrict__ outb,
    float* __restrict__ outT, int m_off) {
    __shared__ ushortT As[3 * 4096];
    __shared__ ushortT Bs[3 * 4096];
    const int tid = threadIdx.x, wave = tid >> 6, lane = tid & 63;
    int tm, tn;
    xcd_remap(tm, tn);

    floatx4 acc[4][4];
    #pragma unroll
    for (int a = 0; a < 4; ++a)
        #pragma unroll
        for (int c = 0; c < 4; ++c)
            acc[a][c] = (floatx4){0.f, 0.f, 0.f, 0.f};

    gemm_core128(A, B, K, tm, tn, As, Bs, acc, tid, wave, lane);

    const int wr = (wave >> 1) * 64, wc = (wave & 1) * 64;
    const int nb = tn * 128 + wc + (lane & 15);
    const int mbl = wr + ((lane >> 4) << 2);
    #pragma unroll
    for (int nt = 0; nt < 4; ++nt) {
        int n = nb + nt * 16;
        float bv = (EPI == 2 || EPI == 3) ? bias[n] : 0.f;
        #pragma unroll
        for (int mt = 0; mt < 4; ++mt) {
            int m0 = tm * 128 + mbl + mt * 16;
            if constexpr (EPI == 1) {
                int bb = m0 / 196, tok = m0 - bb * 196;
                float* p = outT + ((size_t)(bb * 768 + n)) * 196 + tok;
                float hv[4];
                *(float4*)hv = *(const float4*)p;
                float vv[4];
                #pragma unroll
                for (int r = 0; r < 4; ++r) vv[r] = acc[mt][nt][r] + hv[r];
                *(float4*)p = *(const float4*)vv;
                #pragma unroll
                for (int r = 0; r < 4; ++r)
                    outb[(size_t)(m0 + r) * 768 + n] = f2b(vv[r]);
            } else if constexpr (EPI == 2) {
                #pragma unroll
                for (int r = 0; r < 4; ++r) {
                    float v = acc[mt][nt][r] + bv;
                    float gl = 0.5f * v * (1.f + erff(v * 0.70710678118654752f));
                    outb[(size_t)(m0 + r) * 1536 + n] = f2b(gl);
                }
            } else {
                int mg = m0 + m_off;
                int bb = mg / 196, tok = mg - bb * 196;
                float* p = outT + ((size_t)(bb * 768 + n)) * 196 + tok;
                float hv[4];
                *(float4*)hv = *(const float4*)p;
                float vv[4];
                #pragma unroll
                for (int r = 0; r < 4; ++r) vv[r] = acc[mt][nt][r] + bv + hv[r];
                *(float4*)p = *(const float4*)vv;
            }
        }
    }
}

// ---------------------------------------------------------------- launch
extern "C" void kernel_launch(void* const* d_in, const int* in_sizes, int n_in,
                              void* d_out, int out_size, void* d_ws, size_t ws_size,
                              hipStream_t stream) {
    const float* x       = (const float*)d_in[0];
    const float* W_qkv   = (const float*)d_in[1];
    const float* bias_tb = (const float*)d_in[2];
    const float* W_out   = (const float*)d_in[3];
    const float* b_out   = (const float*)d_in[4];
    const float* ln1_g   = (const float*)d_in[5];
    const float* ln1_b   = (const float*)d_in[6];
    const float* ln2_g   = (const float*)d_in[7];
    const float* ln2_b   = (const float*)d_in[8];
    const float* W_fc1   = (const float*)d_in[9];
    const float* b_fc1   = (const float*)d_in[10];
    const float* W_fc2   = (const float*)d_in[11];
    const float* b_fc2   = (const float*)d_in[12];
    const float* W_proj  = (const float*)d_in[13];
    float* out = (float*)d_out;

    char* ws = (char*)d_ws;
    ushortT* pooled = (ushortT*)(ws);                 // [12544][384]
    ushortT* tln1   = (ushortT*)(ws + 9633792);       // [12544][384]
    ushortT* attno  = tln1;                           // reuse
    ushortT* qkvb   = (ushortT*)(ws + 19267584);      // [3][64][8][196][32]
    ushortT* tln2   = qkvb;                           // reuse (after attn)
    ushortT* mid    = (ushortT*)(ws);                 // [6272][1536] reuse (half path)
    ushortT* htok   = (ushortT*)(ws + 38535168);      // [12544][768]
    // bias_exp aliases htok region: written by prep, read by attn, then htok is
    // written (by wout gemm) strictly AFTER attn -> stream-safe.
    float*   bias_exp = (float*)(ws + 38535168);      // 1,384,448 B
    ushortT* wTqkv  = (ushortT*)(ws + 57802752);      // [768][384]
    ushortT* wTout  = wTqkv + 768 * 384;              // [768][256]
    ushortT* wTfc1  = wTout + 768 * 256;              // [1536][768]
    ushortT* wTfc2  = wTfc1 + 1536 * 768;             // [768][1536]
    ushortT* wProjB = wTfc2 + 768 * 1536;             // [768][384]
    const size_t weights_end = 57802752 +
        (size_t)(768 * 384 + 768 * 256 + 1536 * 768 + 768 * 1536 + 768 * 384) * 2;
    const bool ffn_full = ws_size >= weights_end + (size_t)M_TOT * HIDDEN * 2;
    ushortT* midf = (ushortT*)(ws + weights_end);

    // merged weight prep + pool + bias expansion
    prep_pool<<<4946, 256, 0, stream>>>(W_qkv, W_out, W_fc1, W_fc2, W_proj, x, bias_tb,
                                        wTqkv, wTout, wTfc1, wTfc2, wProjB, pooled,
                                        bias_exp);

    // LN1
    ln_kernel<2><<<M_TOT / 4, 256, 0, stream>>>(pooled, ln1_g, ln1_b, tln1);

    // QKV gemm + proj gemm merged (proj -> out fp32 transposed, + b_out)
    gemm_qkvproj<<<dim3(98, 12), 256, 0, stream>>>(tln1, wTqkv, pooled, wProjB,
                                                   b_out, qkvb, out);
    // MFMA attention
    attn_kernel<<<512, 256, 0, stream>>>(qkvb, bias_exp, attno);

    // h = attn_out @ W_out^T + (proj already in out); writes out fp32 + htok bf16
    gemm128p<1><<<dim3(98, 6), 256, 0, stream>>>(attno, wTout, 256,
                                                 nullptr, htok, out, 0);
    // LN2
    ln_kernel<4><<<M_TOT / 4, 256, 0, stream>>>(htok, ln2_g, ln2_b, tln2);

    if (ffn_full) {
        gemm128p<2><<<dim3(98, 12), 256, 0, stream>>>(tln2, wTfc1, 768,
                                                      b_fc1, midf, nullptr, 0);
        gemm128p<3><<<dim3(98, 6), 256, 0, stream>>>(midf, wTfc2, 1536,
                                                     b_fc2, nullptr, out, 0);
    } else {
        for (int half = 0; half < 2; ++half) {
            const ushortT* a2 = tln2 + (size_t)half * M_HALF * 768;
            gemm128p<2><<<dim3(49, 12), 256, 0, stream>>>(a2, wTfc1, 768,
                                                          b_fc1, mid, nullptr, 0);
            gemm128p<3><<<dim3(49, 6), 256, 0, stream>>>(mid, wTfc2, 1536,
                                                         b_fc2, nullptr, out,
                                                         half * M_HALF);
        }
    }
    (void)in_sizes; (void)n_in; (void)out_size; (void)ws_size;
}